// Round 1
// baseline (70.360 us; speedup 1.0000x reference)
//
#include <hip/hip_runtime.h>
#include <math.h>

#define NB 65536
#define PI_F 3.14159265358979323846f

// Per-thread MLP: x[8] -> f[8] through 8->10(relu)->10(relu)->8.
// Weights live in LDS; all lanes read the same address (broadcast).
__device__ __forceinline__ void mlp8(const float x[8],
                                     const float* __restrict__ sW1, const float* __restrict__ sb1,
                                     const float* __restrict__ sW2, const float* __restrict__ sb2,
                                     const float* __restrict__ sW3, const float* __restrict__ sb3,
                                     float f[8]) {
    float h1[10];
#pragma unroll
    for (int i = 0; i < 10; ++i) {
        float s = sb1[i];
#pragma unroll
        for (int j = 0; j < 8; ++j) s = fmaf(x[j], sW1[i * 8 + j], s);
        h1[i] = fmaxf(s, 0.0f);
    }
    float h2[10];
#pragma unroll
    for (int i = 0; i < 10; ++i) {
        float s = sb2[i];
#pragma unroll
        for (int j = 0; j < 10; ++j) s = fmaf(h1[j], sW2[i * 10 + j], s);
        h2[i] = fmaxf(s, 0.0f);
    }
#pragma unroll
    for (int i = 0; i < 8; ++i) {
        float s = sb3[i];
#pragma unroll
        for (int j = 0; j < 10; ++j) s = fmaf(h2[j], sW3[i * 10 + j], s);
        f[i] = s;
    }
}

__global__ __launch_bounds__(256) void hsinner_kernel(
    const float* __restrict__ x1, const float* __restrict__ x2,
    const float* __restrict__ W1, const float* __restrict__ b1,
    const float* __restrict__ W2, const float* __restrict__ b2,
    const float* __restrict__ W3, const float* __restrict__ b3,
    float* __restrict__ out) {
    __shared__ float sW1[80], sb1[10], sW2[100], sb2[10], sW3[80], sb3[8];
    const int t = threadIdx.x;
    if (t < 100) sW2[t] = W2[t];
    if (t < 80) { sW1[t] = W1[t]; sW3[t] = W3[t]; }
    if (t < 10) { sb1[t] = b1[t]; sb2[t] = b2[t]; }
    if (t < 8) sb3[t] = b3[t];
    __syncthreads();

    const int b = blockIdx.x * blockDim.x + t;  // exactly NB threads launched

    // Vector-load the two 8-float inputs (32 B each).
    float X1[8], X2[8];
    {
        const float4* p1 = reinterpret_cast<const float4*>(x1 + (size_t)b * 8);
        const float4* p2 = reinterpret_cast<const float4*>(x2 + (size_t)b * 8);
        float4 a0 = p1[0], a1 = p1[1];
        float4 c0 = p2[0], c1 = p2[1];
        X1[0] = a0.x; X1[1] = a0.y; X1[2] = a0.z; X1[3] = a0.w;
        X1[4] = a1.x; X1[5] = a1.y; X1[6] = a1.z; X1[7] = a1.w;
        X2[0] = c0.x; X2[1] = c0.y; X2[2] = c0.z; X2[3] = c0.w;
        X2[4] = c1.x; X2[5] = c1.y; X2[6] = c1.z; X2[7] = c1.w;
    }

    float f1[8], f2[8];
    mlp8(X1, sW1, sb1, sW2, sb2, sW3, sb3, f1);
    mlp8(X2, sW1, sb1, sW2, sb2, sW3, sb3, f2);

    // d_j = f1_j - f2_j ; e_j = (pi-f1_j)(pi-f1_{j+1}) - (pi-f2_j)(pi-f2_{j+1})
    float d[8], e[7];
#pragma unroll
    for (int j = 0; j < 8; ++j) d[j] = f1[j] - f2[j];
#pragma unroll
    for (int j = 0; j < 7; ++j) {
        float p1a = PI_F - f1[j], p1b = PI_F - f1[j + 1];
        float p2a = PI_F - f2[j], p2b = PI_F - f2[j + 1];
        e[j] = p1a * p1b - p2a * p2b;
    }

    // Sum over the 256 sign patterns via a 2x2 complex transfer-matrix chain:
    //   Z = sum_{s in {+-1}^8} exp(i*(sum_j d_j s_j + sum_j e_j s_j s_{j+1}))
    //   out = Re(Z)/256  (== sum_k cos(a1_k - a2_k)/256; cos is even)
    float sd, cd;
    __sincosf(d[0], &sd, &cd);
    float upr = cd, upi = sd;    // u[+] = e^{+i d0}
    float umr = cd, umi = -sd;   // u[-] = e^{-i d0}
#pragma unroll
    for (int j = 1; j < 8; ++j) {
        float se, ce;
        __sincosf(e[j - 1], &se, &ce);
        // u_p*c, u_p*conj(c), u_m*c, u_m*conj(c) share partial products
        float prc = upr * ce, pis = upi * se, pic = upi * ce, prs = upr * se;
        float mrc = umr * ce, mis = umi * se, mic = umi * ce, mrs = umr * se;
        float ap_r = (prc - pis) + (mrc + mis);  // u_p*c + u_m*conj(c)
        float ap_i = (pic + prs) + (mic - mrs);
        float am_r = (prc + pis) + (mrc - mis);  // u_p*conj(c) + u_m*c
        float am_i = (pic - prs) + (mic + mrs);
        float sdj, cdj;
        __sincosf(d[j], &sdj, &cdj);
        upr = ap_r * cdj - ap_i * sdj;           // * e^{+i d_j}
        upi = ap_r * sdj + ap_i * cdj;
        umr = am_r * cdj + am_i * sdj;           // * e^{-i d_j}
        umi = am_i * cdj - am_r * sdj;
    }

    out[b] = (upr + umr) * (1.0f / 256.0f);
}

extern "C" void kernel_launch(void* const* d_in, const int* in_sizes, int n_in,
                              void* d_out, int out_size, void* d_ws, size_t ws_size,
                              hipStream_t stream) {
    const float* x1 = (const float*)d_in[0];
    const float* x2 = (const float*)d_in[1];
    const float* W1 = (const float*)d_in[2];
    const float* b1 = (const float*)d_in[3];
    const float* W2 = (const float*)d_in[4];
    const float* b2 = (const float*)d_in[5];
    const float* W3 = (const float*)d_in[6];
    const float* b3 = (const float*)d_in[7];
    float* out = (float*)d_out;

    hsinner_kernel<<<NB / 256, 256, 0, stream>>>(x1, x2, W1, b1, W2, b2, W3, b3, out);
}